// Round 2
// baseline (33021.689 us; speedup 1.0000x reference)
//
#include <hip/hip_runtime.h>

#define BATCH 16
#define NPIX 16384      // B*H*W
#define PIMG 1296       // 36*36 padded image
#define PST 20736       // per-channel padded stride = BATCH*PIMG
#define TSTEPS 19

typedef __attribute__((ext_vector_type(8))) short short8;
typedef __attribute__((ext_vector_type(4))) float f32x4;
typedef __attribute__((ext_vector_type(4))) unsigned int uint4v;

__device__ __forceinline__ float bf2f(unsigned short u) {
  union { unsigned int i; float f; } v; v.i = ((unsigned int)u) << 16; return v.f;
}
__device__ __forceinline__ unsigned short f2bf(float f) {
  union { float f; unsigned int i; } v; v.f = f;
  unsigned int r = v.i + 0x7FFFu + ((v.i >> 16) & 1u);
  return (unsigned short)(r >> 16);
}
__device__ __forceinline__ float sigm(float x) { return 1.0f / (1.0f + __expf(-x)); }

struct Job {
  const unsigned short* W;    // [M][Ktot] bf16
  const unsigned short* inP;  // padded input, [Cin][BATCH][36][36] bf16
  unsigned short* out;        // [M][NPIX] bf16
  const int* offtab;          // per-k gather offsets (len >= ceil32(Ktot), -1 = pad)
  int Ktot;
  int yBase;                  // first blockIdx.y tile of this job
  int padAdj;                 // (2-pad)*37 : 0 for 5x5 pad2, 74 for 1x1 pad0
};
struct JobSet { Job jobs[4]; int njobs; };

// ---------------- setup kernels ----------------
__global__ void zero_ws_kernel(uint4v* p, long n16) {
  long i = (long)blockIdx.x * blockDim.x + threadIdx.x;
  long stride = (long)gridDim.x * blockDim.x;
  uint4v z = {0u, 0u, 0u, 0u};
  for (; i < n16; i += stride) p[i] = z;
}

__global__ void cvt_bf16_kernel(const float* __restrict__ s, unsigned short* __restrict__ d, int n) {
  int i = blockIdx.x * 256 + threadIdx.x;
  if (i < n) d[i] = f2bf(s[i]);
}

__global__ void build_offtab_kernel(int* tab, int len, int ktot, int kksq) {
  int k = blockIdx.x * 256 + threadIdx.x;
  if (k >= len) return;
  if (k >= ktot) { tab[k] = -1; return; }
  int ci, dy, dx;
  if (kksq == 25) { ci = k / 25; int tp = k % 25; dy = tp / 5; dx = tp % 5; }
  else           { ci = k; dy = 0; dx = 0; }
  tab[k] = ci * PST + dy * 36 + dx;
}

// ---------------- conv implicit-GEMM ----------------
// Tile: 64 (Cout) x 128 (pixels), 256 threads = 4 waves, each wave 32x64.
// A in LDS [64][56] (padded stride for bank spread), B in LDS [4 kgrp][128 n][8 k].
__global__ __launch_bounds__(256) void conv_gemm(JobSet js) {
  __shared__ __align__(16) unsigned short Alds[64 * 56];
  __shared__ __align__(16) unsigned short Blds[4 * 128 * 8];

  int by = blockIdx.y;
  Job jb = js.jobs[0];
#pragma unroll
  for (int q = 1; q < 4; q++)
    if (q < js.njobs && by >= js.jobs[q].yBase) jb = js.jobs[q];
  int m0 = (by - jb.yBase) * 64;

  int t = threadIdx.x;
  int lane = t & 63;
  int wave = t >> 6;
  // B gather mapping: thread handles one n, two k-groups
  int nloc = t & 127;
  int kgBase = (t >> 7) * 2;
  int nglob = blockIdx.x * 128 + nloc;
  int bb = nglob >> 10, rem = nglob & 1023;
  int yy = rem >> 5, xx = rem & 31;
  int nbase = bb * PIMG + yy * 36 + xx + jb.padAdj;
  // A stage mapping: thread loads 8 bf16 of one row
  int arow = t >> 2, achunk = (t & 3) * 8;
  // wave tile
  int wm = (wave >> 1) * 32, wn = (wave & 1) * 64;

  f32x4 acc[2][4];
#pragma unroll
  for (int mf = 0; mf < 2; mf++)
#pragma unroll
    for (int nf = 0; nf < 4; nf++) acc[mf][nf] = (f32x4){0.f, 0.f, 0.f, 0.f};

  const unsigned short* Arow = jb.W + (long)(m0 + arow) * jb.Ktot;
  int Ksteps = (jb.Ktot + 31) >> 5;

  for (int ks = 0; ks < Ksteps; ks++) {
    int k0 = ks << 5;
    // --- load A chunk (to regs) ---
    short8 av = (short8){0, 0, 0, 0, 0, 0, 0, 0};
    int ak = k0 + achunk;
    if (ak < jb.Ktot) av = *(const short8*)(Arow + ak);
    // --- gather B (to regs) ---
    short8 bvv[2];
#pragma unroll
    for (int g = 0; g < 2; g++) {
      int kk = k0 + (kgBase + g) * 8;
      const int* ot = jb.offtab + kk;
#pragma unroll
      for (int q = 0; q < 8; q++) {
        int off = ot[q];
        unsigned short v = (off >= 0) ? jb.inP[nbase + off] : (unsigned short)0;
        bvv[g][q] = (short)v;
      }
    }
    __syncthreads();   // previous compute done reading LDS
    *(short8*)(Alds + arow * 56 + achunk) = av;
#pragma unroll
    for (int g = 0; g < 2; g++)
      *(short8*)(Blds + ((kgBase + g) * 128 + nloc) * 8) = bvv[g];
    __syncthreads();
    // --- compute ---
    int mrow = wm + (lane & 15);
    int kg = lane >> 4;
    short8 af0 = *(const short8*)(Alds + mrow * 56 + kg * 8);
    short8 af1 = *(const short8*)(Alds + (mrow + 16) * 56 + kg * 8);
    short8 bf[4];
#pragma unroll
    for (int nf = 0; nf < 4; nf++)
      bf[nf] = *(const short8*)(Blds + (kg * 128 + wn + nf * 16 + (lane & 15)) * 8);
#pragma unroll
    for (int nf = 0; nf < 4; nf++) {
      acc[0][nf] = __builtin_amdgcn_mfma_f32_16x16x32_bf16(af0, bf[nf], acc[0][nf], 0, 0, 0);
      acc[1][nf] = __builtin_amdgcn_mfma_f32_16x16x32_bf16(af1, bf[nf], acc[1][nf], 0, 0, 0);
    }
  }
  // --- epilogue: C/D layout col=lane&15 (pixel), row=(lane>>4)*4+v (cout) ---
  int colb = blockIdx.x * 128 + wn + (lane & 15);
  int rowb = m0 + wm + (lane >> 4) * 4;
#pragma unroll
  for (int mf = 0; mf < 2; mf++)
#pragma unroll
    for (int nf = 0; nf < 4; nf++)
#pragma unroll
      for (int v = 0; v < 4; v++)
        jb.out[(long)(rowb + mf * 16 + v) * NPIX + colb + nf * 16] = f2bf(acc[mf][nf][v]);
}

// ---------------- pointwise kernels ----------------
__global__ void gates1_kernel(const unsigned short* __restrict__ xc,
                              const unsigned short* __restrict__ hc,
                              const unsigned short* __restrict__ mc,
                              float* __restrict__ cSt, float* __restrict__ mSt,
                              unsigned short* __restrict__ mP,
                              unsigned short* __restrict__ memP) {
  int idx = blockIdx.x * 256 + threadIdx.x;  // 64*16384
  int ch = idx >> 14, n = idx & 16383;
  float i_x = bf2f(xc[(long)(ch) * NPIX + n]);
  float f_x = bf2f(xc[(long)(64 + ch) * NPIX + n]);
  float g_x = bf2f(xc[(long)(128 + ch) * NPIX + n]);
  float ipx = bf2f(xc[(long)(192 + ch) * NPIX + n]);
  float fpx = bf2f(xc[(long)(256 + ch) * NPIX + n]);
  float gpx = bf2f(xc[(long)(320 + ch) * NPIX + n]);
  float i_h = bf2f(hc[(long)(ch) * NPIX + n]);
  float f_h = bf2f(hc[(long)(64 + ch) * NPIX + n]);
  float g_h = bf2f(hc[(long)(128 + ch) * NPIX + n]);
  float i_m = bf2f(mc[(long)(ch) * NPIX + n]);
  float f_m = bf2f(mc[(long)(64 + ch) * NPIX + n]);
  float g_m = bf2f(mc[(long)(128 + ch) * NPIX + n]);
  float it = sigm(i_x + i_h);
  float ft = sigm(f_x + f_h + 1.0f);
  float gt = tanhf(g_x + g_h);
  float cn = ft * cSt[idx] + it * gt;
  float itp = sigm(ipx + i_m);
  float ftp = sigm(fpx + f_m + 1.0f);
  float gtp = tanhf(gpx + g_m);
  float mn = ftp * mSt[idx] + itp * gtp;
  cSt[idx] = cn;
  mSt[idx] = mn;
  int bb = n >> 10, yy = (n >> 5) & 31, xx = n & 31;
  int pidx = ch * PST + bb * PIMG + (yy + 2) * 36 + (xx + 2);
  mP[pidx] = f2bf(mn);
  memP[pidx] = f2bf(cn);
  memP[pidx + 64 * PST] = f2bf(mn);
}

__global__ void gates2_kernel(const unsigned short* __restrict__ xc,
                              const unsigned short* __restrict__ hc,
                              const unsigned short* __restrict__ oo,
                              const unsigned short* __restrict__ ll,
                              unsigned short* __restrict__ hP) {
  int idx = blockIdx.x * 256 + threadIdx.x;  // 64*16384
  int ch = idx >> 14, n = idx & 16383;
  float opre = bf2f(xc[(long)(384 + ch) * NPIX + n]) +
               bf2f(hc[(long)(192 + ch) * NPIX + n]) +
               bf2f(oo[(long)ch * NPIX + n]);
  float h = sigm(opre) * tanhf(bf2f(ll[(long)ch * NPIX + n]));
  int bb = n >> 10, yy = (n >> 5) & 31, xx = n & 31;
  hP[ch * PST + bb * PIMG + (yy + 2) * 36 + (xx + 2)] = f2bf(h);
}

__global__ void net_kernel(const float* __restrict__ frames,
                           const float* __restrict__ mask_true,
                           const float* __restrict__ xgen,
                           unsigned short* __restrict__ netP, int tstep) {
  int idx = blockIdx.x * 256 + threadIdx.x;  // 16*16384
  int c = idx >> 14, n = idx & 16383;
  int bb = n >> 10, yx = n & 1023;
  float fr = frames[((long)(bb * 20 + tstep) * 16 + c) * 1024 + yx];
  float v;
  if (tstep < 10) {
    v = fr;
  } else {
    float mk = mask_true[((long)(bb * 9 + (tstep - 10)) * 16 + c) * 1024 + yx];
    v = mk * fr + (1.0f - mk) * xgen[(long)c * NPIX + n];
  }
  int yy = yx >> 5, xx = yx & 31;
  netP[c * PST + bb * PIMG + (yy + 2) * 36 + (xx + 2)] = f2bf(v);
}

__global__ void xgen_kernel(const unsigned short* __restrict__ hP3,
                            const float* __restrict__ Wlast,
                            float* __restrict__ xgen, float* __restrict__ out,
                            int tstep) {
  int idx = blockIdx.x * 256 + threadIdx.x;  // 16*16384
  int co = idx >> 14, n = idx & 16383;
  int bb = n >> 10, yx = n & 1023;
  int yy = yx >> 5, xx = yx & 31;
  int pbase = bb * PIMG + (yy + 2) * 36 + (xx + 2);
  float s = 0.f;
#pragma unroll
  for (int ci = 0; ci < 64; ci++)
    s += Wlast[co * 64 + ci] * bf2f(hP3[ci * PST + pbase]);
  xgen[(long)co * NPIX + n] = s;
  out[((long)(bb * TSTEPS + tstep) * 16 + co) * 1024 + yx] = s;
}

// ---------------- host ----------------
extern "C" void kernel_launch(void* const* d_in, const int* in_sizes, int n_in,
                              void* d_out, int out_size, void* d_ws, size_t ws_size,
                              hipStream_t stream) {
  (void)in_sizes; (void)n_in; (void)out_size; (void)ws_size;
  const float* frames    = (const float*)d_in[0];
  const float* mask_true = (const float*)d_in[1];
  const float* Wx0       = (const float*)d_in[2];
  const float* Wxr       = (const float*)d_in[3];
  const float* Wh        = (const float*)d_in[4];
  const float* Wm        = (const float*)d_in[5];
  const float* Wo        = (const float*)d_in[6];
  const float* Wl        = (const float*)d_in[7];
  const float* Wlast     = (const float*)d_in[8];
  float* out = (float*)d_out;

  char* ws = (char*)d_ws;
  size_t cur = 0;
  auto alloc = [&](size_t bytes) -> char* {
    cur = (cur + 255) & ~(size_t)255;
    char* p = ws + cur;
    cur += bytes;
    return p;
  };

  // ---- zero-init region (padded activations + recurrent state) ----
  unsigned short* netP = (unsigned short*)alloc((size_t)16 * PST * 2);
  unsigned short* hP[4];
  for (int l = 0; l < 4; l++) hP[l] = (unsigned short*)alloc((size_t)64 * PST * 2);
  unsigned short* mP   = (unsigned short*)alloc((size_t)64 * PST * 2);
  unsigned short* memP = (unsigned short*)alloc((size_t)128 * PST * 2);
  float* cSt   = (float*)alloc((size_t)4 * 64 * NPIX * 4);
  float* mSt   = (float*)alloc((size_t)64 * NPIX * 4);
  float* xgenB = (float*)alloc((size_t)16 * NPIX * 4);
  size_t zeroEnd = cur;

  // ---- weights (bf16) ----
  unsigned short* WxBF0 = (unsigned short*)alloc((size_t)448 * 400 * 2);
  unsigned short* WxrBF = (unsigned short*)alloc((size_t)3 * 448 * 1600 * 2);
  unsigned short* WhBF  = (unsigned short*)alloc((size_t)4 * 256 * 1600 * 2);
  unsigned short* WmBF  = (unsigned short*)alloc((size_t)4 * 192 * 1600 * 2);
  unsigned short* WoBF  = (unsigned short*)alloc((size_t)4 * 64 * 3200 * 2);
  unsigned short* WlBF  = (unsigned short*)alloc((size_t)4 * 64 * 128 * 2);
  int* ot16  = (int*)alloc(416 * 4);
  int* ot64  = (int*)alloc(1600 * 4);
  int* ot128 = (int*)alloc(3200 * 4);
  int* ot1   = (int*)alloc(128 * 4);

  // ---- conv output buffers (bf16) ----
  unsigned short* xcB = (unsigned short*)alloc((size_t)448 * NPIX * 2);
  unsigned short* hcB = (unsigned short*)alloc((size_t)4 * 256 * NPIX * 2);
  unsigned short* mcB = (unsigned short*)alloc((size_t)192 * NPIX * 2);
  unsigned short* ooB = (unsigned short*)alloc((size_t)64 * NPIX * 2);
  unsigned short* llB = (unsigned short*)alloc((size_t)64 * NPIX * 2);

  // ---- setup ----
  zero_ws_kernel<<<1024, 256, 0, stream>>>((uint4v*)ws, (long)(zeroEnd / 16));
  {
    int n;
    n = 448 * 400;        cvt_bf16_kernel<<<(n + 255) / 256, 256, 0, stream>>>(Wx0, WxBF0, n);
    n = 3 * 448 * 1600;   cvt_bf16_kernel<<<(n + 255) / 256, 256, 0, stream>>>(Wxr, WxrBF, n);
    n = 4 * 256 * 1600;   cvt_bf16_kernel<<<(n + 255) / 256, 256, 0, stream>>>(Wh, WhBF, n);
    n = 4 * 192 * 1600;   cvt_bf16_kernel<<<(n + 255) / 256, 256, 0, stream>>>(Wm, WmBF, n);
    n = 4 * 64 * 3200;    cvt_bf16_kernel<<<(n + 255) / 256, 256, 0, stream>>>(Wo, WoBF, n);
    n = 4 * 64 * 128;     cvt_bf16_kernel<<<(n + 255) / 256, 256, 0, stream>>>(Wl, WlBF, n);
  }
  build_offtab_kernel<<<2, 256, 0, stream>>>(ot16, 416, 400, 25);
  build_offtab_kernel<<<7, 256, 0, stream>>>(ot64, 1600, 1600, 25);
  build_offtab_kernel<<<13, 256, 0, stream>>>(ot128, 3200, 3200, 25);
  build_offtab_kernel<<<1, 256, 0, stream>>>(ot1, 128, 128, 1);

  // ---- time loop ----
  for (int t = 0; t < TSTEPS; t++) {
    net_kernel<<<1024, 256, 0, stream>>>(frames, mask_true, xgenB, netP, t);

    // hc for all 4 layers (reads previous-timestep h)
    JobSet hs{};
    hs.njobs = 4;
    for (int z = 0; z < 4; z++)
      hs.jobs[z] = Job{ WhBF + (size_t)z * 256 * 1600, hP[z], hcB + (size_t)z * 256 * NPIX,
                        ot64, 1600, z * 4, 0 };
    conv_gemm<<<dim3(128, 16), 256, 0, stream>>>(hs);

    for (int l = 0; l < 4; l++) {
      // xc (input: net for l=0, h[l-1] otherwise) + mc (input: m)
      JobSet ca{};
      ca.njobs = 2;
      if (l == 0) ca.jobs[0] = Job{ WxBF0, netP, xcB, ot16, 400, 0, 0 };
      else        ca.jobs[0] = Job{ WxrBF + (size_t)(l - 1) * 448 * 1600, hP[l - 1], xcB, ot64, 1600, 0, 0 };
      ca.jobs[1] = Job{ WmBF + (size_t)l * 192 * 1600, mP, mcB, ot64, 1600, 7, 0 };
      conv_gemm<<<dim3(128, 10), 256, 0, stream>>>(ca);

      gates1_kernel<<<4096, 256, 0, stream>>>(xcB, hcB + (size_t)l * 256 * NPIX, mcB,
                                              cSt + (size_t)l * 64 * NPIX, mSt, mP, memP);

      // wo (5x5 over mem) + wl (1x1 over mem)
      JobSet cb{};
      cb.njobs = 2;
      cb.jobs[0] = Job{ WoBF + (size_t)l * 64 * 3200, memP, ooB, ot128, 3200, 0, 0 };
      cb.jobs[1] = Job{ WlBF + (size_t)l * 64 * 128, memP, llB, ot1, 128, 1, 74 };
      conv_gemm<<<dim3(128, 2), 256, 0, stream>>>(cb);

      gates2_kernel<<<4096, 256, 0, stream>>>(xcB, hcB + (size_t)l * 256 * NPIX, ooB, llB, hP[l]);
    }

    xgen_kernel<<<1024, 256, 0, stream>>>(hP[3], Wlast, xgenB, out, t);
  }
}

// Round 4
// 17542.259 us; speedup vs baseline: 1.8824x; 1.8824x over previous
//
#include <hip/hip_runtime.h>

#define BATCH 16
#define NPIX 16384      // B*H*W
#define PIMG 1296       // 36*36 padded image
#define PST 20736       // per-channel padded stride = BATCH*PIMG
#define TSTEPS 19
#define SPLITWO 4       // split-K chunks for the wo conv (3200 -> 4x800)

typedef __attribute__((ext_vector_type(8))) short short8;
typedef __attribute__((ext_vector_type(4))) float f32x4;
typedef __attribute__((ext_vector_type(4))) unsigned int uint4v;
typedef __attribute__((ext_vector_type(4))) int int4v;

__device__ __forceinline__ float bf2f(unsigned short u) {
  union { unsigned int i; float f; } v; v.i = ((unsigned int)u) << 16; return v.f;
}
__device__ __forceinline__ unsigned short f2bf(float f) {
  union { float f; unsigned int i; } v; v.f = f;
  unsigned int r = v.i + 0x7FFFu + ((v.i >> 16) & 1u);
  return (unsigned short)(r >> 16);
}
__device__ __forceinline__ float sigm(float x) { return 1.0f / (1.0f + __expf(-x)); }

struct Job {
  const unsigned short* W;    // [M][Kstride] bf16 (chunk base pre-added)
  const unsigned short* inP;  // padded input, [Cin][BATCH][36][36] bf16
  unsigned short* out;        // bf16 out [M][NPIX] (used when outF==null)
  float* outF;                // f32 out [M][NPIX] (split-K partials)
  const int* offtab;          // per-k gather offsets (-1 = pad)
  int Ktot;                   // K iteration extent for this job/chunk
  int Kstride;                // A row stride (full K of the weight)
  int yBase;                  // first blockIdx.y tile of this job
  int padAdj;                 // 0 for 5x5 pad2, 74 for 1x1 pad0
};
struct JobSet { Job jobs[6]; int njobs; };

// ---------------- setup kernels ----------------
__global__ void zero_ws_kernel(uint4v* p, long n16) {
  long i = (long)blockIdx.x * blockDim.x + threadIdx.x;
  long stride = (long)gridDim.x * blockDim.x;
  uint4v z = {0u, 0u, 0u, 0u};
  for (; i < n16; i += stride) p[i] = z;
}

__global__ void cvt_bf16_kernel(const float* __restrict__ s, unsigned short* __restrict__ d, int n) {
  int i = blockIdx.x * 256 + threadIdx.x;
  if (i < n) d[i] = f2bf(s[i]);
}

__global__ void build_offtab_kernel(int* tab, int len, int ktot, int kksq) {
  int k = blockIdx.x * 256 + threadIdx.x;
  if (k >= len) return;
  if (k >= ktot) { tab[k] = -1; return; }
  int ci, dy, dx;
  if (kksq == 25) { ci = k / 25; int tp = k % 25; dy = tp / 5; dx = tp % 5; }
  else           { ci = k; dy = 0; dx = 0; }
  tab[k] = ci * PST + dy * 36 + dx;
}

// ---------------- conv implicit-GEMM (pipelined, double-buffered) ----------------
// Tile: 64 (Cout) x 128 (pixels), 256 threads = 4 waves, each wave 32x64.
// A LDS [2][64][40] (stride 40 elem: 16B-aligned rows, 2-way bank alias = free),
// B LDS [2][4 kgrp][128 n][8 k]. One barrier per K-step; gather for ks+1 is
// issued before the MFMA of ks so vmem latency hides under compute.
__global__ __launch_bounds__(256) void conv_gemm(JobSet js) {
  __shared__ __align__(16) unsigned short Alds[2][64 * 40];
  __shared__ __align__(16) unsigned short Blds[2][4 * 128 * 8];

  int by = blockIdx.y;
  Job jb = js.jobs[0];
#pragma unroll
  for (int q = 1; q < 6; q++)
    if (q < js.njobs && by >= js.jobs[q].yBase) jb = js.jobs[q];
  int m0 = (by - jb.yBase) * 64;

  int t = threadIdx.x;
  int lane = t & 63;
  int wave = t >> 6;
  // B gather mapping: thread handles one n, two k-groups
  int nloc = t & 127;
  int kgBase = (t >> 7) * 2;
  int nglob = blockIdx.x * 128 + nloc;
  int bb = nglob >> 10, rem = nglob & 1023;
  int yy = rem >> 5, xx = rem & 31;
  int nbase = bb * PIMG + yy * 36 + xx + jb.padAdj;
  // A stage mapping: thread loads 8 bf16 of one row
  int arow = t >> 2, achunk = (t & 3) * 8;
  // wave tile
  int wm = (wave >> 1) * 32, wn = (wave & 1) * 64;

  f32x4 acc[2][4];
#pragma unroll
  for (int mf = 0; mf < 2; mf++)
#pragma unroll
    for (int nf = 0; nf < 4; nf++) acc[mf][nf] = (f32x4){0.f, 0.f, 0.f, 0.f};

  const unsigned short* Arow = jb.W + (long)(m0 + arow) * jb.Kstride;
  int Ksteps = (jb.Ktot + 31) >> 5;

  short8 avR;
  short8 bvR[2];

  auto gather = [&](int ks) {
    int k0 = ks << 5;
    int ak = k0 + achunk;
    short8 z = (short8){0, 0, 0, 0, 0, 0, 0, 0};
    avR = (ak < jb.Ktot) ? *(const short8*)(Arow + ak) : z;
#pragma unroll
    for (int g = 0; g < 2; g++) {
      int kk = k0 + (kgBase + g) * 8;
      int4v o0 = *(const int4v*)(jb.offtab + kk);
      int4v o1 = *(const int4v*)(jb.offtab + kk + 4);
#pragma unroll
      for (int q = 0; q < 4; q++) {
        int off = o0[q];
        bvR[g][q] = (off >= 0) ? (short)jb.inP[nbase + off] : (short)0;
      }
#pragma unroll
      for (int q = 0; q < 4; q++) {
        int off = o1[q];
        bvR[g][4 + q] = (off >= 0) ? (short)jb.inP[nbase + off] : (short)0;
      }
    }
  };
  auto stash = [&](int buf) {
    *(short8*)(&Alds[buf][arow * 40 + achunk]) = avR;
#pragma unroll
    for (int g = 0; g < 2; g++)
      *(short8*)(&Blds[buf][((kgBase + g) * 128 + nloc) * 8]) = bvR[g];
  };

  gather(0);
  stash(0);
  int cur = 0;
  int mrow = wm + (lane & 15);
  int kg = lane >> 4;

  for (int ks = 0; ks < Ksteps; ks++) {
    __syncthreads();                       // buf[cur] staged & prior reads done
    if (ks + 1 < Ksteps) gather(ks + 1);   // vmem in flight during compute
    short8 af0 = *(const short8*)(&Alds[cur][mrow * 40 + kg * 8]);
    short8 af1 = *(const short8*)(&Alds[cur][(mrow + 16) * 40 + kg * 8]);
    short8 bf[4];
#pragma unroll
    for (int nf = 0; nf < 4; nf++)
      bf[nf] = *(const short8*)(&Blds[cur][(kg * 128 + wn + nf * 16 + (lane & 15)) * 8]);
#pragma unroll
    for (int nf = 0; nf < 4; nf++) {
      acc[0][nf] = __builtin_amdgcn_mfma_f32_16x16x32_bf16(af0, bf[nf], acc[0][nf], 0, 0, 0);
      acc[1][nf] = __builtin_amdgcn_mfma_f32_16x16x32_bf16(af1, bf[nf], acc[1][nf], 0, 0, 0);
    }
    if (ks + 1 < Ksteps) stash(cur ^ 1);   // write other buffer (no conflict)
    cur ^= 1;
  }

  // epilogue: C/D layout col=lane&15 (pixel), row=(lane>>4)*4+v (cout)
  int colb = blockIdx.x * 128 + wn + (lane & 15);
  int rowb = m0 + wm + (lane >> 4) * 4;
  if (jb.outF) {
#pragma unroll
    for (int mf = 0; mf < 2; mf++)
#pragma unroll
      for (int nf = 0; nf < 4; nf++)
#pragma unroll
        for (int v = 0; v < 4; v++)
          jb.outF[(long)(rowb + mf * 16 + v) * NPIX + colb + nf * 16] = acc[mf][nf][v];
  } else {
#pragma unroll
    for (int mf = 0; mf < 2; mf++)
#pragma unroll
      for (int nf = 0; nf < 4; nf++)
#pragma unroll
        for (int v = 0; v < 4; v++)
          jb.out[(long)(rowb + mf * 16 + v) * NPIX + colb + nf * 16] = f2bf(acc[mf][nf][v]);
  }
}

// ---------------- pointwise kernels ----------------
__global__ void gates1_kernel(const unsigned short* __restrict__ xc,
                              const unsigned short* __restrict__ hc,
                              const unsigned short* __restrict__ mc,
                              float* __restrict__ cSt, float* __restrict__ mSt,
                              unsigned short* __restrict__ mP,
                              unsigned short* __restrict__ memP) {
  int idx = blockIdx.x * 256 + threadIdx.x;  // 64*16384
  int ch = idx >> 14, n = idx & 16383;
  float i_x = bf2f(xc[(long)(ch) * NPIX + n]);
  float f_x = bf2f(xc[(long)(64 + ch) * NPIX + n]);
  float g_x = bf2f(xc[(long)(128 + ch) * NPIX + n]);
  float ipx = bf2f(xc[(long)(192 + ch) * NPIX + n]);
  float fpx = bf2f(xc[(long)(256 + ch) * NPIX + n]);
  float gpx = bf2f(xc[(long)(320 + ch) * NPIX + n]);
  float i_h = bf2f(hc[(long)(ch) * NPIX + n]);
  float f_h = bf2f(hc[(long)(64 + ch) * NPIX + n]);
  float g_h = bf2f(hc[(long)(128 + ch) * NPIX + n]);
  float i_m = bf2f(mc[(long)(ch) * NPIX + n]);
  float f_m = bf2f(mc[(long)(64 + ch) * NPIX + n]);
  float g_m = bf2f(mc[(long)(128 + ch) * NPIX + n]);
  float it = sigm(i_x + i_h);
  float ft = sigm(f_x + f_h + 1.0f);
  float gt = tanhf(g_x + g_h);
  float cn = ft * cSt[idx] + it * gt;
  float itp = sigm(ipx + i_m);
  float ftp = sigm(fpx + f_m + 1.0f);
  float gtp = tanhf(gpx + g_m);
  float mn = ftp * mSt[idx] + itp * gtp;
  cSt[idx] = cn;
  mSt[idx] = mn;
  int bb = n >> 10, yy = (n >> 5) & 31, xx = n & 31;
  int pidx = ch * PST + bb * PIMG + (yy + 2) * 36 + (xx + 2);
  mP[pidx] = f2bf(mn);
  memP[pidx] = f2bf(cn);
  memP[pidx + 64 * PST] = f2bf(mn);
}

__global__ void gates2_kernel(const unsigned short* __restrict__ xc,
                              const unsigned short* __restrict__ hc,
                              const float* __restrict__ woPart,
                              const unsigned short* __restrict__ ll,
                              unsigned short* __restrict__ hP) {
  int idx = blockIdx.x * 256 + threadIdx.x;  // 64*16384
  int ch = idx >> 14, n = idx & 16383;
  float osum = 0.f;
#pragma unroll
  for (int c = 0; c < SPLITWO; c++)
    osum += woPart[((long)c * 64 + ch) * NPIX + n];
  float opre = bf2f(xc[(long)(384 + ch) * NPIX + n]) +
               bf2f(hc[(long)(192 + ch) * NPIX + n]) + osum;
  float h = sigm(opre) * tanhf(bf2f(ll[(long)ch * NPIX + n]));
  int bb = n >> 10, yy = (n >> 5) & 31, xx = n & 31;
  hP[ch * PST + bb * PIMG + (yy + 2) * 36 + (xx + 2)] = f2bf(h);
}

__global__ void net_kernel(const float* __restrict__ frames,
                           const float* __restrict__ mask_true,
                           const float* __restrict__ xgen,
                           unsigned short* __restrict__ netP, int tstep) {
  int idx = blockIdx.x * 256 + threadIdx.x;  // 16*16384
  int c = idx >> 14, n = idx & 16383;
  int bb = n >> 10, yx = n & 1023;
  float fr = frames[((long)(bb * 20 + tstep) * 16 + c) * 1024 + yx];
  float v;
  if (tstep < 10) {
    v = fr;
  } else {
    float mk = mask_true[((long)(bb * 9 + (tstep - 10)) * 16 + c) * 1024 + yx];
    v = mk * fr + (1.0f - mk) * xgen[(long)c * NPIX + n];
  }
  int yy = yx >> 5, xx = yx & 31;
  netP[c * PST + bb * PIMG + (yy + 2) * 36 + (xx + 2)] = f2bf(v);
}

__global__ void xgen_kernel(const unsigned short* __restrict__ hP3,
                            const float* __restrict__ Wlast,
                            float* __restrict__ xgen, float* __restrict__ out,
                            int tstep) {
  int idx = blockIdx.x * 256 + threadIdx.x;  // 16*16384
  int co = idx >> 14, n = idx & 16383;
  int bb = n >> 10, yx = n & 1023;
  int yy = yx >> 5, xx = yx & 31;
  int pbase = bb * PIMG + (yy + 2) * 36 + (xx + 2);
  float s = 0.f;
#pragma unroll
  for (int ci = 0; ci < 64; ci++)
    s += Wlast[co * 64 + ci] * bf2f(hP3[ci * PST + pbase]);
  xgen[(long)co * NPIX + n] = s;
  out[((long)(bb * TSTEPS + tstep) * 16 + co) * 1024 + yx] = s;
}

// ---------------- host ----------------
extern "C" void kernel_launch(void* const* d_in, const int* in_sizes, int n_in,
                              void* d_out, int out_size, void* d_ws, size_t ws_size,
                              hipStream_t stream) {
  (void)in_sizes; (void)n_in; (void)out_size; (void)ws_size;
  const float* frames    = (const float*)d_in[0];
  const float* mask_true = (const float*)d_in[1];
  const float* Wx0       = (const float*)d_in[2];
  const float* Wxr       = (const float*)d_in[3];
  const float* Wh        = (const float*)d_in[4];
  const float* Wm        = (const float*)d_in[5];
  const float* Wo        = (const float*)d_in[6];
  const float* Wl        = (const float*)d_in[7];
  const float* Wlast     = (const float*)d_in[8];
  float* out = (float*)d_out;

  char* ws = (char*)d_ws;
  size_t cur = 0;
  auto alloc = [&](size_t bytes) -> char* {
    cur = (cur + 255) & ~(size_t)255;
    char* p = ws + cur;
    cur += bytes;
    return p;
  };

  // ---- zero-init region (padded activations + recurrent state) ----
  unsigned short* netP = (unsigned short*)alloc((size_t)16 * PST * 2);
  unsigned short* hP[4];
  for (int l = 0; l < 4; l++) hP[l] = (unsigned short*)alloc((size_t)64 * PST * 2);
  unsigned short* mP   = (unsigned short*)alloc((size_t)64 * PST * 2);
  unsigned short* memP = (unsigned short*)alloc((size_t)128 * PST * 2);
  float* cSt   = (float*)alloc((size_t)4 * 64 * NPIX * 4);
  float* mSt   = (float*)alloc((size_t)64 * NPIX * 4);
  float* xgenB = (float*)alloc((size_t)16 * NPIX * 4);
  size_t zeroEnd = cur;

  // ---- weights (bf16) ----
  unsigned short* WxBF0 = (unsigned short*)alloc((size_t)448 * 400 * 2);
  unsigned short* WxrBF = (unsigned short*)alloc((size_t)3 * 448 * 1600 * 2);
  unsigned short* WhBF  = (unsigned short*)alloc((size_t)4 * 256 * 1600 * 2);
  unsigned short* WmBF  = (unsigned short*)alloc((size_t)4 * 192 * 1600 * 2);
  unsigned short* WoBF  = (unsigned short*)alloc((size_t)4 * 64 * 3200 * 2);
  unsigned short* WlBF  = (unsigned short*)alloc((size_t)4 * 64 * 128 * 2);
  int* ot16  = (int*)alloc(416 * 4);
  int* ot64  = (int*)alloc(1600 * 4);
  int* ot128 = (int*)alloc(3200 * 4);
  int* ot1   = (int*)alloc(128 * 4);

  // ---- conv output buffers ----
  unsigned short* xcB = (unsigned short*)alloc((size_t)448 * NPIX * 2);
  unsigned short* hcB = (unsigned short*)alloc((size_t)256 * NPIX * 2);
  unsigned short* mcB = (unsigned short*)alloc((size_t)192 * NPIX * 2);
  unsigned short* llB = (unsigned short*)alloc((size_t)64 * NPIX * 2);
  float* woPart = (float*)alloc((size_t)SPLITWO * 64 * NPIX * 4);

  // ---- setup ----
  zero_ws_kernel<<<1024, 256, 0, stream>>>((uint4v*)ws, (long)(zeroEnd / 16));
  {
    int n;
    n = 448 * 400;        cvt_bf16_kernel<<<(n + 255) / 256, 256, 0, stream>>>(Wx0, WxBF0, n);
    n = 3 * 448 * 1600;   cvt_bf16_kernel<<<(n + 255) / 256, 256, 0, stream>>>(Wxr, WxrBF, n);
    n = 4 * 256 * 1600;   cvt_bf16_kernel<<<(n + 255) / 256, 256, 0, stream>>>(Wh, WhBF, n);
    n = 4 * 192 * 1600;   cvt_bf16_kernel<<<(n + 255) / 256, 256, 0, stream>>>(Wm, WmBF, n);
    n = 4 * 64 * 3200;    cvt_bf16_kernel<<<(n + 255) / 256, 256, 0, stream>>>(Wo, WoBF, n);
    n = 4 * 64 * 128;     cvt_bf16_kernel<<<(n + 255) / 256, 256, 0, stream>>>(Wl, WlBF, n);
  }
  build_offtab_kernel<<<2, 256, 0, stream>>>(ot16, 416, 400, 25);
  build_offtab_kernel<<<7, 256, 0, stream>>>(ot64, 1600, 1600, 25);
  build_offtab_kernel<<<13, 256, 0, stream>>>(ot128, 3200, 3200, 25);
  build_offtab_kernel<<<1, 256, 0, stream>>>(ot1, 128, 128, 1);

  // ---- time loop ----
  for (int t = 0; t < TSTEPS; t++) {
    net_kernel<<<1024, 256, 0, stream>>>(frames, mask_true, xgenB, netP, t);

    for (int l = 0; l < 4; l++) {
      // xc (net for l=0, h[l-1] new value otherwise) + mc (m) + hc (h[l] OLD value:
      // hP[l] still holds h(l, t-1) until gates2(l) overwrites it below)
      JobSet ca{};
      ca.njobs = 3;
      if (l == 0) ca.jobs[0] = Job{ WxBF0, netP, xcB, nullptr, ot16, 400, 400, 0, 0 };
      else        ca.jobs[0] = Job{ WxrBF + (size_t)(l - 1) * 448 * 1600, hP[l - 1], xcB, nullptr, ot64, 1600, 1600, 0, 0 };
      ca.jobs[1] = Job{ WmBF + (size_t)l * 192 * 1600, mP, mcB, nullptr, ot64, 1600, 1600, 7, 0 };
      ca.jobs[2] = Job{ WhBF + (size_t)l * 256 * 1600, hP[l], hcB, nullptr, ot64, 1600, 1600, 10, 0 };
      conv_gemm<<<dim3(128, 14), 256, 0, stream>>>(ca);

      gates1_kernel<<<4096, 256, 0, stream>>>(xcB, hcB, mcB,
                                              cSt + (size_t)l * 64 * NPIX, mSt, mP, memP);

      // wo (5x5 over mem, split-K x4 -> f32 partials) + wl (1x1 over mem)
      JobSet cb{};
      cb.njobs = SPLITWO + 1;
      for (int c = 0; c < SPLITWO; c++)
        cb.jobs[c] = Job{ WoBF + (size_t)l * 64 * 3200 + 800 * c, memP, nullptr,
                          woPart + (size_t)c * 64 * NPIX, ot128 + 800 * c, 800, 3200, c, 0 };
      cb.jobs[SPLITWO] = Job{ WlBF + (size_t)l * 64 * 128, memP, llB, nullptr, ot1, 128, 128, SPLITWO, 74 };
      conv_gemm<<<dim3(128, SPLITWO + 1), 256, 0, stream>>>(cb);

      gates2_kernel<<<4096, 256, 0, stream>>>(xcB, hcB, woPart, llB, hP[l]);
    }

    xgen_kernel<<<1024, 256, 0, stream>>>(hP[3], Wlast, xgenB, out, t);
  }
}

// Round 6
// 14651.636 us; speedup vs baseline: 2.2538x; 1.1973x over previous
//
#include <hip/hip_runtime.h>

#define BATCH 16
#define NPIX 16384      // B*H*W
#define PIMG 1296       // 36*36 padded image
#define PST 20736       // per-channel padded stride = BATCH*PIMG
#define TSTEPS 19
#define SPLITWO 4       // split-K chunks for the wo conv (3200 -> 4x800)

typedef __attribute__((ext_vector_type(8))) short short8;
typedef __attribute__((ext_vector_type(4))) float f32x4;
typedef __attribute__((ext_vector_type(4))) unsigned int uint4v;
typedef __attribute__((ext_vector_type(4))) int int4v;

__device__ __forceinline__ float bf2f(unsigned short u) {
  union { unsigned int i; float f; } v; v.i = ((unsigned int)u) << 16; return v.f;
}
__device__ __forceinline__ unsigned short f2bf(float f) {
  union { float f; unsigned int i; } v; v.f = f;
  unsigned int r = v.i + 0x7FFFu + ((v.i >> 16) & 1u);
  return (unsigned short)(r >> 16);
}
__device__ __forceinline__ float sigm(float x) { return 1.0f / (1.0f + __expf(-x)); }

struct Job {
  const unsigned short* W;    // [M][Kstride] bf16 (chunk base pre-added)
  const unsigned short* inP;  // padded input, [Cin][BATCH][36][36] bf16
  unsigned short* out;        // bf16 out [M][NPIX] (used when outF==null)
  float* outF;                // f32 out [M][NPIX] (split-K partials)
  const int* offtab2;         // per-k gather BYTE offsets (tail-padded with 0)
  int Ktot;                   // K extent (multiple of 32)
  int Kstride;                // A row stride in elements (full K of the weight)
  int yBase;                  // first blockIdx.y tile of this job
  int padAdj;                 // 0 for 5x5 pad2, 74 for 1x1 pad0 (elements)
  int Mtot;                   // valid output rows
};
struct JobSet { Job jobs[6]; int njobs; };

// ---------------- setup kernels ----------------
__global__ void zero_ws_kernel(uint4v* p, long n16) {
  long i = (long)blockIdx.x * blockDim.x + threadIdx.x;
  long stride = (long)gridDim.x * blockDim.x;
  uint4v z = {0u, 0u, 0u, 0u};
  for (; i < n16; i += stride) p[i] = z;
}

__global__ void cvt_bf16_kernel(const float* __restrict__ s, unsigned short* __restrict__ d, int n) {
  int i = blockIdx.x * 256 + threadIdx.x;
  if (i < n) d[i] = f2bf(s[i]);
}

// Wx0 [448][400] -> [448][416] with zero-padded K tail (kills all predication)
__global__ void cvt_pad_wx0_kernel(const float* __restrict__ s, unsigned short* __restrict__ d) {
  int i = blockIdx.x * 256 + threadIdx.x;
  if (i >= 448 * 416) return;
  int r = i / 416, k = i - r * 416;
  d[i] = (k < 400) ? f2bf(s[r * 400 + k]) : (unsigned short)0;
}

// byte offsets; tail entries (k>=ktot) -> 0 (valid addr, weight row is zero there)
__global__ void build_offtab_kernel(int* tab, int len, int ktot, int kksq) {
  int k = blockIdx.x * 256 + threadIdx.x;
  if (k >= len) return;
  if (k >= ktot) { tab[k] = 0; return; }
  int ci, dy, dx;
  if (kksq == 25) { ci = k / 25; int tp = k % 25; dy = tp / 5; dx = tp % 5; }
  else           { ci = k; dy = 0; dx = 0; }
  tab[k] = (ci * PST + dy * 36 + dx) * 2;
}

// ---------------- conv implicit-GEMM: direct-gather, no LDS, no barriers -----
// Block 128x128 (Cout x pixels) = 4 independent waves of 64x64.
// Per K-step(32) per wave: 4x dwordx4 A loads, 2x int4 offset loads,
// 32 ushort B gathers, 16 MFMA. Software-pipelined 2-deep in registers.
__global__ __launch_bounds__(256, 2) void conv_gemm(JobSet js) {
  int by = blockIdx.y;
  Job jb = js.jobs[0];
#pragma unroll
  for (int q = 1; q < 6; q++)
    if (q < js.njobs && by >= js.jobs[q].yBase) jb = js.jobs[q];
  int m0 = (by - jb.yBase) * 128;

  int t = threadIdx.x;
  int lane = t & 63;
  int wave = t >> 6;
  int l15 = lane & 15, kg = lane >> 4;
  int wm = (wave >> 1) * 64, wn = (wave & 1) * 64;

  // B pixel byte-bases for the 4 n-fragments
  int nb2[4];
#pragma unroll
  for (int nf = 0; nf < 4; nf++) {
    int ng = blockIdx.x * 128 + wn + nf * 16 + l15;
    int bb = ng >> 10, rem = ng & 1023;
    int yy = rem >> 5, xx = rem & 31;
    nb2[nf] = (bb * PIMG + yy * 36 + xx + jb.padAdj) * 2;
  }
  // A element-offsets for the 4 m-fragments (row-clamped; stores guarded below)
  int aoff[4];
#pragma unroll
  for (int mf = 0; mf < 4; mf++) {
    int r = m0 + wm + mf * 16 + l15;
    if (r > jb.Mtot - 1) r = jb.Mtot - 1;
    aoff[mf] = r * jb.Kstride + kg * 8;
  }

  f32x4 acc[4][4];
#pragma unroll
  for (int mf = 0; mf < 4; mf++)
#pragma unroll
    for (int nf = 0; nf < 4; nf++) acc[mf][nf] = (f32x4){0.f, 0.f, 0.f, 0.f};

  const unsigned short* Wp = jb.W;
  const char* ip = (const char*)jb.inP;
  const int* ot = jb.offtab2;

  short8 af0[4], bf0[4], af1[4], bf1[4];

  auto loadA = [&](short8* af, int k0) {
#pragma unroll
    for (int mf = 0; mf < 4; mf++)
      af[mf] = *(const short8*)(Wp + aoff[mf] + k0);
  };
  auto loadB = [&](short8* bfv, int k0) {
    const int* otp = ot + k0 + kg * 8;
    int4v o0 = *(const int4v*)(otp);
    int4v o1 = *(const int4v*)(otp + 4);
#pragma unroll
    for (int nf = 0; nf < 4; nf++) {
      short8 v;
#pragma unroll
      for (int q = 0; q < 4; q++)
        v[q] = (short)*(const unsigned short*)(ip + nb2[nf] + o0[q]);
#pragma unroll
      for (int q = 0; q < 4; q++)
        v[4 + q] = (short)*(const unsigned short*)(ip + nb2[nf] + o1[q]);
      bfv[nf] = v;
    }
  };
  auto domfma = [&](short8* af, short8* bfv) {
#pragma unroll
    for (int mf = 0; mf < 4; mf++)
#pragma unroll
      for (int nf = 0; nf < 4; nf++)
        acc[mf][nf] = __builtin_amdgcn_mfma_f32_16x16x32_bf16(af[mf], bfv[nf], acc[mf][nf], 0, 0, 0);
  };

  int K = jb.Ktot;
  loadA(af0, 0); loadB(bf0, 0);
  int k0 = 0;
  while (true) {
    int kn = k0 + 32;
    if (kn < K) { loadA(af1, kn); loadB(bf1, kn); }
    domfma(af0, bf0);
    k0 = kn; if (k0 >= K) break;
    kn = k0 + 32;
    if (kn < K) { loadA(af0, kn); loadB(bf0, kn); }
    domfma(af1, bf1);
    k0 = kn; if (k0 >= K) break;
  }

  // epilogue: C/D layout col=lane&15 (pixel), row=(lane>>4)*4+v (cout)
  int colb = blockIdx.x * 128 + wn + l15;
  int rowb = m0 + wm + (lane >> 4) * 4;
  if (jb.outF) {
#pragma unroll
    for (int mf = 0; mf < 4; mf++) {
      if (m0 + wm + mf * 16 >= jb.Mtot) continue;   // wave-uniform guard
#pragma unroll
      for (int nf = 0; nf < 4; nf++)
#pragma unroll
        for (int v = 0; v < 4; v++)
          jb.outF[(long)(rowb + mf * 16 + v) * NPIX + colb + nf * 16] = acc[mf][nf][v];
    }
  } else {
#pragma unroll
    for (int mf = 0; mf < 4; mf++) {
      if (m0 + wm + mf * 16 >= jb.Mtot) continue;
#pragma unroll
      for (int nf = 0; nf < 4; nf++)
#pragma unroll
        for (int v = 0; v < 4; v++)
          jb.out[(long)(rowb + mf * 16 + v) * NPIX + colb + nf * 16] = f2bf(acc[mf][nf][v]);
    }
  }
}

// ---------------- pointwise kernels ----------------
__global__ void gates1_kernel(const unsigned short* __restrict__ xc,
                              const unsigned short* __restrict__ hc,
                              const unsigned short* __restrict__ mc,
                              float* __restrict__ cSt, float* __restrict__ mSt,
                              unsigned short* __restrict__ mP,
                              unsigned short* __restrict__ memP) {
  int idx = blockIdx.x * 256 + threadIdx.x;  // 64*16384
  int ch = idx >> 14, n = idx & 16383;
  float i_x = bf2f(xc[(long)(ch) * NPIX + n]);
  float f_x = bf2f(xc[(long)(64 + ch) * NPIX + n]);
  float g_x = bf2f(xc[(long)(128 + ch) * NPIX + n]);
  float ipx = bf2f(xc[(long)(192 + ch) * NPIX + n]);
  float fpx = bf2f(xc[(long)(256 + ch) * NPIX + n]);
  float gpx = bf2f(xc[(long)(320 + ch) * NPIX + n]);
  float i_h = bf2f(hc[(long)(ch) * NPIX + n]);
  float f_h = bf2f(hc[(long)(64 + ch) * NPIX + n]);
  float g_h = bf2f(hc[(long)(128 + ch) * NPIX + n]);
  float i_m = bf2f(mc[(long)(ch) * NPIX + n]);
  float f_m = bf2f(mc[(long)(64 + ch) * NPIX + n]);
  float g_m = bf2f(mc[(long)(128 + ch) * NPIX + n]);
  float it = sigm(i_x + i_h);
  float ft = sigm(f_x + f_h + 1.0f);
  float gt = tanhf(g_x + g_h);
  float cn = ft * cSt[idx] + it * gt;
  float itp = sigm(ipx + i_m);
  float ftp = sigm(fpx + f_m + 1.0f);
  float gtp = tanhf(gpx + g_m);
  float mn = ftp * mSt[idx] + itp * gtp;
  cSt[idx] = cn;
  mSt[idx] = mn;
  int bb = n >> 10, yy = (n >> 5) & 31, xx = n & 31;
  int pidx = ch * PST + bb * PIMG + (yy + 2) * 36 + (xx + 2);
  mP[pidx] = f2bf(mn);
  memP[pidx] = f2bf(cn);
  memP[pidx + 64 * PST] = f2bf(mn);
}

__global__ void gates2_kernel(const unsigned short* __restrict__ xc,
                              const unsigned short* __restrict__ hc,
                              const float* __restrict__ woPart,
                              const unsigned short* __restrict__ ll,
                              unsigned short* __restrict__ hP) {
  int idx = blockIdx.x * 256 + threadIdx.x;  // 64*16384
  int ch = idx >> 14, n = idx & 16383;
  float osum = 0.f;
#pragma unroll
  for (int c = 0; c < SPLITWO; c++)
    osum += woPart[((long)c * 64 + ch) * NPIX + n];
  float opre = bf2f(xc[(long)(384 + ch) * NPIX + n]) +
               bf2f(hc[(long)(192 + ch) * NPIX + n]) + osum;
  float h = sigm(opre) * tanhf(bf2f(ll[(long)ch * NPIX + n]));
  int bb = n >> 10, yy = (n >> 5) & 31, xx = n & 31;
  hP[ch * PST + bb * PIMG + (yy + 2) * 36 + (xx + 2)] = f2bf(h);
}

__global__ void net_kernel(const float* __restrict__ frames,
                           const float* __restrict__ mask_true,
                           const float* __restrict__ xgen,
                           unsigned short* __restrict__ netP, int tstep) {
  int idx = blockIdx.x * 256 + threadIdx.x;  // 16*16384
  int c = idx >> 14, n = idx & 16383;
  int bb = n >> 10, yx = n & 1023;
  float fr = frames[((long)(bb * 20 + tstep) * 16 + c) * 1024 + yx];
  float v;
  if (tstep < 10) {
    v = fr;
  } else {
    float mk = mask_true[((long)(bb * 9 + (tstep - 10)) * 16 + c) * 1024 + yx];
    v = mk * fr + (1.0f - mk) * xgen[(long)c * NPIX + n];
  }
  int yy = yx >> 5, xx = yx & 31;
  netP[c * PST + bb * PIMG + (yy + 2) * 36 + (xx + 2)] = f2bf(v);
}

__global__ void xgen_kernel(const unsigned short* __restrict__ hP3,
                            const float* __restrict__ Wlast,
                            float* __restrict__ xgen, float* __restrict__ out,
                            int tstep) {
  int idx = blockIdx.x * 256 + threadIdx.x;  // 16*16384
  int co = idx >> 14, n = idx & 16383;
  int bb = n >> 10, yx = n & 1023;
  int yy = yx >> 5, xx = yx & 31;
  int pbase = bb * PIMG + (yy + 2) * 36 + (xx + 2);
  float s = 0.f;
#pragma unroll
  for (int ci = 0; ci < 64; ci++)
    s += Wlast[co * 64 + ci] * bf2f(hP3[ci * PST + pbase]);
  xgen[(long)co * NPIX + n] = s;
  out[((long)(bb * TSTEPS + tstep) * 16 + co) * 1024 + yx] = s;
}

// ---------------- host ----------------
extern "C" void kernel_launch(void* const* d_in, const int* in_sizes, int n_in,
                              void* d_out, int out_size, void* d_ws, size_t ws_size,
                              hipStream_t stream) {
  (void)in_sizes; (void)n_in; (void)out_size; (void)ws_size;
  const float* frames    = (const float*)d_in[0];
  const float* mask_true = (const float*)d_in[1];
  const float* Wx0       = (const float*)d_in[2];
  const float* Wxr       = (const float*)d_in[3];
  const float* Wh        = (const float*)d_in[4];
  const float* Wm        = (const float*)d_in[5];
  const float* Wo        = (const float*)d_in[6];
  const float* Wl        = (const float*)d_in[7];
  const float* Wlast     = (const float*)d_in[8];
  float* out = (float*)d_out;

  char* ws = (char*)d_ws;
  size_t cur = 0;
  auto alloc = [&](size_t bytes) -> char* {
    cur = (cur + 255) & ~(size_t)255;
    char* p = ws + cur;
    cur += bytes;
    return p;
  };

  // ---- zero-init region (padded activations + recurrent state) ----
  unsigned short* netP = (unsigned short*)alloc((size_t)16 * PST * 2);
  unsigned short* hP[4];
  for (int l = 0; l < 4; l++) hP[l] = (unsigned short*)alloc((size_t)64 * PST * 2);
  unsigned short* mP   = (unsigned short*)alloc((size_t)64 * PST * 2);
  unsigned short* memP = (unsigned short*)alloc((size_t)128 * PST * 2);
  float* cSt   = (float*)alloc((size_t)4 * 64 * NPIX * 4);
  float* mSt   = (float*)alloc((size_t)64 * NPIX * 4);
  float* xgenB = (float*)alloc((size_t)16 * NPIX * 4);
  size_t zeroEnd = cur;

  // ---- weights (bf16) ----
  unsigned short* WxBF0 = (unsigned short*)alloc((size_t)448 * 416 * 2);  // K-padded
  unsigned short* WxrBF = (unsigned short*)alloc((size_t)3 * 448 * 1600 * 2);
  unsigned short* WhBF  = (unsigned short*)alloc((size_t)4 * 256 * 1600 * 2);
  unsigned short* WmBF  = (unsigned short*)alloc((size_t)4 * 192 * 1600 * 2);
  unsigned short* WoBF  = (unsigned short*)alloc((size_t)4 * 64 * 3200 * 2);
  unsigned short* WlBF  = (unsigned short*)alloc((size_t)4 * 64 * 128 * 2);
  int* ot16  = (int*)alloc(416 * 4);
  int* ot64  = (int*)alloc(1600 * 4);
  int* ot128 = (int*)alloc(3200 * 4);
  int* ot1   = (int*)alloc(128 * 4);

  // ---- conv output buffers ----
  unsigned short* xcB = (unsigned short*)alloc((size_t)448 * NPIX * 2);
  unsigned short* hcB = (unsigned short*)alloc((size_t)256 * NPIX * 2);
  unsigned short* mcB = (unsigned short*)alloc((size_t)192 * NPIX * 2);
  unsigned short* llB = (unsigned short*)alloc((size_t)64 * NPIX * 2);
  float* woPart = (float*)alloc((size_t)SPLITWO * 64 * NPIX * 4);

  // ---- setup ----
  zero_ws_kernel<<<1024, 256, 0, stream>>>((uint4v*)ws, (long)(zeroEnd / 16));
  {
    int n;
    n = 448 * 416;        cvt_pad_wx0_kernel<<<(n + 255) / 256, 256, 0, stream>>>(Wx0, WxBF0);
    n = 3 * 448 * 1600;   cvt_bf16_kernel<<<(n + 255) / 256, 256, 0, stream>>>(Wxr, WxrBF, n);
    n = 4 * 256 * 1600;   cvt_bf16_kernel<<<(n + 255) / 256, 256, 0, stream>>>(Wh, WhBF, n);
    n = 4 * 192 * 1600;   cvt_bf16_kernel<<<(n + 255) / 256, 256, 0, stream>>>(Wm, WmBF, n);
    n = 4 * 64 * 3200;    cvt_bf16_kernel<<<(n + 255) / 256, 256, 0, stream>>>(Wo, WoBF, n);
    n = 4 * 64 * 128;     cvt_bf16_kernel<<<(n + 255) / 256, 256, 0, stream>>>(Wl, WlBF, n);
  }
  build_offtab_kernel<<<2, 256, 0, stream>>>(ot16, 416, 400, 25);
  build_offtab_kernel<<<7, 256, 0, stream>>>(ot64, 1600, 1600, 25);
  build_offtab_kernel<<<13, 256, 0, stream>>>(ot128, 3200, 3200, 25);
  build_offtab_kernel<<<1, 256, 0, stream>>>(ot1, 128, 128, 1);

  // ---- time loop ----
  for (int t = 0; t < TSTEPS; t++) {
    net_kernel<<<1024, 256, 0, stream>>>(frames, mask_true, xgenB, netP, t);

    for (int l = 0; l < 4; l++) {
      // xc (net for l=0, h[l-1] new value otherwise) + mc (m) + hc (h[l] OLD value:
      // hP[l] still holds h(l, t-1) until gates2(l) overwrites it below)
      // M-tiles of 128: xc 448->4, mc 192->2, hc 256->2  => grid y = 8
      JobSet ca{};
      ca.njobs = 3;
      if (l == 0) ca.jobs[0] = Job{ WxBF0, netP, xcB, nullptr, ot16, 416, 416, 0, 0, 448 };
      else        ca.jobs[0] = Job{ WxrBF + (size_t)(l - 1) * 448 * 1600, hP[l - 1], xcB, nullptr, ot64, 1600, 1600, 0, 0, 448 };
      ca.jobs[1] = Job{ WmBF + (size_t)l * 192 * 1600, mP, mcB, nullptr, ot64, 1600, 1600, 4, 0, 192 };
      ca.jobs[2] = Job{ WhBF + (size_t)l * 256 * 1600, hP[l], hcB, nullptr, ot64, 1600, 1600, 6, 0, 256 };
      conv_gemm<<<dim3(128, 8), 256, 0, stream>>>(ca);

      gates1_kernel<<<4096, 256, 0, stream>>>(xcB, hcB, mcB,
                                              cSt + (size_t)l * 64 * NPIX, mSt, mP, memP);

      // wo (5x5 over mem, split-K x4 -> f32 partials, M=64) + wl (1x1, M=64)
      JobSet cb{};
      cb.njobs = SPLITWO + 1;
      for (int c = 0; c < SPLITWO; c++)
        cb.jobs[c] = Job{ WoBF + (size_t)l * 64 * 3200 + 800 * c, memP, nullptr,
                          woPart + (size_t)c * 64 * NPIX, ot128 + 800 * c, 800, 3200, c, 0, 64 };
      cb.jobs[SPLITWO] = Job{ WlBF + (size_t)l * 64 * 128, memP, llB, nullptr, ot1, 128, 128, SPLITWO, 74, 64 };
      conv_gemm<<<dim3(128, SPLITWO + 1), 256, 0, stream>>>(cb);

      gates2_kernel<<<4096, 256, 0, stream>>>(xcB, hcB, woPart, llB, hP[l]);
    }

    xgen_kernel<<<1024, 256, 0, stream>>>(hP[3], Wlast, xgenB, out, t);
  }
}